// Round 6
// baseline (231.354 us; speedup 1.0000x reference)
//
#include <hip/hip_runtime.h>
#include <hip/hip_bf16.h>

typedef unsigned short u16;
typedef unsigned char u8;
typedef unsigned int u32;
typedef _Float16 f16;
typedef _Float16 f16x8 __attribute__((ext_vector_type(8)));
typedef float f32x4 __attribute__((ext_vector_type(4)));
typedef unsigned int u32x4 __attribute__((ext_vector_type(4)));
typedef unsigned int u32x2 __attribute__((ext_vector_type(2)));
typedef long v2i64 __attribute__((ext_vector_type(2)));

constexpr int BATCH = 2048;
constexpr int DIM   = 512;
constexpr int NCLS  = 10000;
constexpr int NPAD  = 10240;   // 80 * 128 (zero-padded rows)

#define F_S     30.0f
#define F_COS_M 0.9800665778412416f
#define F_SIN_M 0.19866933079506122f
#define F_TH   (-0.9800665778412416f)
#define F_MM    0.03973386615901224f

#define G_AAM  1280   // 16 bm x 80 bn (128x128 tiles)
#define G_CC    512   // 16 bm x 32 bn (128x64 tiles)

static __device__ __forceinline__ float clampf(float v, float lo, float hi) {
    return fminf(fmaxf(v, lo), hi);
}
static __device__ __forceinline__ u32 pk4_fp8(float a, float b, float c, float d) {
    u32 w = __builtin_amdgcn_cvt_pk_fp8_f32(a, b, 0, false);
    w = __builtin_amdgcn_cvt_pk_fp8_f32(c, d, w, true);
    return w;
}
// async global->LDS, 16B/lane. DEST must be wave-uniform base + lane*16; SOURCE may scatter per-lane.
static __device__ __forceinline__ void glds16(const void* g, void* l) {
    __builtin_amdgcn_global_load_lds(
        (const __attribute__((address_space(1))) unsigned int*)g,
        (__attribute__((address_space(3))) unsigned int*)l, 16, 0, 0);
}
static __device__ __forceinline__ float blk_sum(float v, float* sh, int t) {
#pragma unroll
    for (int o = 32; o > 0; o >>= 1) v += __shfl_down(v, o, 64);
    __syncthreads();
    if ((t & 63) == 0) sh[t >> 6] = v;
    __syncthreads();
    return sh[0] + sh[1] + sh[2] + sh[3];
}

// ============ normalize: one WAVE per row -> fp8 e4m3, ks-interleaved rows, COALESCED stores ============
// Byte blk*64+q*16+ks*8 holds k=blk*64+ks*32+q*8 (same permutation for ALL matrices -> dot invariant),
// realized via lane-permute shfl so stores stay lane-contiguous.
__global__ __launch_bounds__(256) void norm_all_kernel(const float* __restrict__ x,
                                                       const float* __restrict__ w,
                                                       const float* __restrict__ wm,
                                                       const float* __restrict__ wn,
                                                       const int* __restrict__ label,
                                                       u8* __restrict__ xnb,
                                                       u8* __restrict__ wb,
                                                       u8* __restrict__ wqb,
                                                       u8* __restrict__ wkb,
                                                       float* __restrict__ zacc) {
    const int t = threadIdx.x, lane = t & 63, wv = t >> 6;
    const int b = blockIdx.x;
    if (b < 33) zacc[b * 256 + t] = 0.f;   // zero accumulators (8448 >= 8385 used)

    const int row = b * 4 + wv;
    const float* src;
    u8* dst;
    if (row < BATCH) {
        src = x + (size_t)row * DIM;
        dst = xnb + (size_t)row * DIM;
    } else if (row < BATCH + NPAD) {
        const int r = row - BATCH;
        dst = wb + (size_t)r * DIM;
        if (r >= NCLS) {   // zero pad rows (wave-uniform)
            u32x2 z = {0, 0};
            *(u32x2*)(dst + lane * 8) = z;
            return;
        }
        src = w + (size_t)r * DIM;
    } else if (row < BATCH + NPAD + BATCH) {
        const int i = row - (BATCH + NPAD);
        src = wm + (size_t)label[i] * DIM;
        dst = wqb + (size_t)i * DIM;
    } else {
        const int i = row - (BATCH + NPAD + BATCH);
        src = wn + (size_t)label[i] * DIM;
        dst = wkb + (size_t)i * DIM;
    }
    const float4 v0 = ((const float4*)src)[lane * 2];
    const float4 v1 = ((const float4*)src)[lane * 2 + 1];
    float s = v0.x * v0.x + v0.y * v0.y + v0.z * v0.z + v0.w * v0.w
            + v1.x * v1.x + v1.y * v1.y + v1.z * v1.z + v1.w * v1.w;
#pragma unroll
    for (int o = 32; o > 0; o >>= 1) s += __shfl_xor(s, o, 64);
    const float inv = 1.0f / fmaxf(sqrtf(s), 1e-12f);
    u32 lo = pk4_fp8(v0.x * inv, v0.y * inv, v0.z * inv, v0.w * inv);
    u32 hi = pk4_fp8(v1.x * inv, v1.y * inv, v1.z * inv, v1.w * inv);
    const int p = 8 * (lane >> 3) + 4 * (lane & 1) + ((lane >> 1) & 3);
    u32x2 o2;
    o2[0] = __shfl(lo, p, 64);
    o2[1] = __shfl(hi, p, 64);
    *(u32x2*)(dst + lane * 8) = o2;
}

// ============ FUSED fp8 GEMM, BK=64 DOUBLE-BUFFERED pipeline (T3+T4+T5) ============
// [0,1280)=AAM 128x128, [1280,1792)=CC 128x64.
// Per K-step: issue next tile's 4 global_load_lds -> s_waitcnt vmcnt(4) (counted: current
// tile landed, NEXT tile stays in flight across the barrier) -> raw s_barrier -> ds_read
// + setprio(1) MFMA setprio(0) -> lgkmcnt(0) + s_barrier.
// LDS = EXACTLY 32768 B (2x8K A + 2x8K B): red0/red1 are ALIASED into sA[0] (epilogue-only,
// after the K-loop's final barrier when sA is dead) -> 5 blocks/CU (5*32768 = 160 KiB exact),
// 20 waves/CU vs 16 before (+25% latency-hiding supply for the barrier/vmcnt stalls).
__global__ __launch_bounds__(256, 5) void gemm_fused_kernel(const u8* __restrict__ A,
                                                            const u8* __restrict__ Bw,
                                                            const u8* __restrict__ Bq,
                                                            const u8* __restrict__ Bk,
                                                            const int* __restrict__ label,
                                                            float* __restrict__ sumexp,
                                                            float* __restrict__ sumlogit,
                                                            float* __restrict__ philab,
                                                            f16* __restrict__ sim,
                                                            float* __restrict__ msum,
                                                            float* __restrict__ mcnt,
                                                            float* __restrict__ ap) {
    __shared__ __align__(16) u8 sA[2][8192];   // 16 KB (dbuf A: 128 rows x 64B); epilogue: red0/red1
    __shared__ __align__(16) u8 sB[2][8192];   // 16 KB (AAM: B 128x64B; CC: Q=[0,4K), K=[4K,8K))
    float* red0 = (float*)&sA[0][0];           // 128 floats, valid ONLY after K-loop
    float* red1 = (float*)&sA[0][512];         // 128 floats

    const int t = threadIdx.x;
    const int lane = t & 63, wave = t >> 6;
    const int fr = lane & 15, quad = lane >> 4;
    const int gl = quad ^ ((fr >> 1) & 3);      // read-side swizzled 16B granule (of 4)

    const int srow = t >> 2;                    // 0..63 (+64 on second shot)
    const int sg   = (t & 3) ^ ((t >> 3) & 3);  // store-side swizzled source granule

    if (blockIdx.x < G_AAM) {
        // ---------------- AAM: 128x128 tile, BK=64 dbuf, 8 kb ----------------
        const int flat = blockIdx.x;
        const int xcd = flat & 7, r = flat >> 3;
        const int bm = r & 15;
        const int bn = (r >> 4) * 8 + xcd;       // 10 bn per xcd -> per-XCD L2-resident

        const int wm = (wave >> 1) * 64, wn = (wave & 1) * 64;
        const u8* ag = A  + (size_t)(bm * 128 + srow) * DIM + sg * 16;
        const u8* bg = Bw + (size_t)(bn * 128 + srow) * DIM + sg * 16;

        f32x4 acc[4][4] = {};

#define STAGE_AAM(buf, ko)                                              \
        do {                                                            \
            glds16(ag + (ko),            &sA[buf][t * 16]);             \
            glds16(ag + 64 * DIM + (ko), &sA[buf][4096 + t * 16]);      \
            glds16(bg + (ko),            &sB[buf][t * 16]);             \
            glds16(bg + 64 * DIM + (ko), &sB[buf][4096 + t * 16]);      \
        } while (0)

        STAGE_AAM(0, 0);
#pragma unroll
        for (int kb = 0; kb < 8; kb++) {
            const int cur = kb & 1;
            if (kb < 7) {
                STAGE_AAM(cur ^ 1, (kb + 1) * 64);
                asm volatile("s_waitcnt vmcnt(4)" ::: "memory");   // current tile landed; next stays in flight
            } else {
                asm volatile("s_waitcnt vmcnt(0)" ::: "memory");
            }
            __builtin_amdgcn_s_barrier();
            asm volatile("" ::: "memory");       // pin ds_reads below the barrier

            const u8* sAc = sA[cur];
            const u8* sBc = sB[cur];
            v2i64 a8[4], b8[4];
#pragma unroll
            for (int f = 0; f < 4; f++) {
                a8[f] = __builtin_bit_cast(v2i64, *(const u32x4*)&sAc[(wm + f * 16 + fr) * 64 + gl * 16]);
                b8[f] = __builtin_bit_cast(v2i64, *(const u32x4*)&sBc[(wn + f * 16 + fr) * 64 + gl * 16]);
            }
            __builtin_amdgcn_s_setprio(1);
#pragma unroll
            for (int i = 0; i < 4; i++)
#pragma unroll
                for (int j = 0; j < 4; j++) {
                    acc[i][j] = __builtin_amdgcn_mfma_f32_16x16x32_fp8_fp8(a8[i][0], b8[j][0], acc[i][j], 0, 0, 0);
                    acc[i][j] = __builtin_amdgcn_mfma_f32_16x16x32_fp8_fp8(a8[i][1], b8[j][1], acc[i][j], 0, 0, 0);
                }
            __builtin_amdgcn_s_setprio(0);
            asm volatile("s_waitcnt lgkmcnt(0)" ::: "memory");     // our reads consumed -> buffer reusable
            __builtin_amdgcn_s_barrier();
            asm volatile("" ::: "memory");       // pin next stage below the barrier
        }
#undef STAGE_AAM

        // sA is dead now -> carve reduction arrays out of it, zero, sync.
        if (t < 128) { red0[t] = 0.f; red1[t] = 0.f; }
        __syncthreads();

        // Epilogue: per-row partial Σexp(logit), Σlogit (logits<=30 -> fp32 safe, no max-sub)
#pragma unroll
        for (int i = 0; i < 4; i++) {
#pragma unroll
            for (int r3 = 0; r3 < 4; r3++) {
                const int ml = wm + i * 16 + quad * 4 + r3;
                const int mg = bm * 128 + ml;
                const int lab = label[mg];
                float esum = 0.f, lsum = 0.f;
#pragma unroll
                for (int j = 0; j < 4; j++) {
                    const int ng = bn * 128 + wn + j * 16 + fr;
                    if (ng < NCLS) {
                        float cv = acc[i][j][r3];
                        float logit;
                        if (ng == lab) {
                            float sine = sqrtf(clampf(1.f - cv * cv, 0.f, 1.f));
                            float phi = cv * F_COS_M - sine * F_SIN_M;
                            float val = ((cv - F_TH) > 0.f) ? phi : (cv - F_MM);
                            logit = F_S * val;
                            philab[mg] = logit;
                        } else {
                            logit = F_S * cv;
                        }
                        esum += __expf(logit);
                        lsum += logit;
                    }
                }
#pragma unroll
                for (int off = 1; off < 16; off <<= 1) {
                    esum += __shfl_xor(esum, off, 64);
                    lsum += __shfl_xor(lsum, off, 64);
                }
                if (fr == 0) {
                    atomicAdd(&red0[ml], esum);
                    atomicAdd(&red1[ml], lsum);
                }
            }
        }
        __syncthreads();
        if (t < 128) {
            atomicAdd(&sumexp[bm * 128 + t], red0[t]);
            atomicAdd(&sumlogit[bm * 128 + t], red1[t]);
        }
    } else {
        // ---------------- CC: dual GEMM, 128x64 tile, BK=64 dbuf, 8 kb ----------------
        const int c = blockIdx.x - G_AAM;
        const int xcd = c & 7, r = c >> 3;
        const int bm = r & 15;
        const int bn = (r >> 4) * 8 + xcd;       // 0..31

        const int wm = (wave >> 1) * 64, wn = (wave & 1) * 32;

        const u8* ag = A  + (size_t)(bm * 128 + srow) * DIM + sg * 16;
        const u8* qg = Bq + (size_t)(bn * 64 + srow) * DIM + sg * 16;
        const u8* kg = Bk + (size_t)(bn * 64 + srow) * DIM + sg * 16;

        f32x4 aq[4][2] = {};
        f32x4 ak[4][2] = {};

#define STAGE_CC(buf, ko)                                               \
        do {                                                            \
            glds16(ag + (ko),            &sA[buf][t * 16]);             \
            glds16(ag + 64 * DIM + (ko), &sA[buf][4096 + t * 16]);      \
            glds16(qg + (ko),            &sB[buf][t * 16]);             \
            glds16(kg + (ko),            &sB[buf][4096 + t * 16]);      \
        } while (0)

        STAGE_CC(0, 0);
#pragma unroll
        for (int kb = 0; kb < 8; kb++) {
            const int cur = kb & 1;
            if (kb < 7) {
                STAGE_CC(cur ^ 1, (kb + 1) * 64);
                asm volatile("s_waitcnt vmcnt(4)" ::: "memory");
            } else {
                asm volatile("s_waitcnt vmcnt(0)" ::: "memory");
            }
            __builtin_amdgcn_s_barrier();
            asm volatile("" ::: "memory");

            const u8* sAc = sA[cur];
            const u8* sBc = sB[cur];
            v2i64 a8[4], q8[2], k8[2];
#pragma unroll
            for (int f = 0; f < 4; f++)
                a8[f] = __builtin_bit_cast(v2i64, *(const u32x4*)&sAc[(wm + f * 16 + fr) * 64 + gl * 16]);
#pragma unroll
            for (int f = 0; f < 2; f++) {
                q8[f] = __builtin_bit_cast(v2i64, *(const u32x4*)&sBc[(wn + f * 16 + fr) * 64 + gl * 16]);
                k8[f] = __builtin_bit_cast(v2i64, *(const u32x4*)&sBc[4096 + (wn + f * 16 + fr) * 64 + gl * 16]);
            }
            __builtin_amdgcn_s_setprio(1);
#pragma unroll
            for (int i = 0; i < 4; i++)
#pragma unroll
                for (int j = 0; j < 2; j++) {
                    aq[i][j] = __builtin_amdgcn_mfma_f32_16x16x32_fp8_fp8(a8[i][0], q8[j][0], aq[i][j], 0, 0, 0);
                    aq[i][j] = __builtin_amdgcn_mfma_f32_16x16x32_fp8_fp8(a8[i][1], q8[j][1], aq[i][j], 0, 0, 0);
                    ak[i][j] = __builtin_amdgcn_mfma_f32_16x16x32_fp8_fp8(a8[i][0], k8[j][0], ak[i][j], 0, 0, 0);
                    ak[i][j] = __builtin_amdgcn_mfma_f32_16x16x32_fp8_fp8(a8[i][1], k8[j][1], ak[i][j], 0, 0, 0);
                }
            __builtin_amdgcn_s_setprio(0);
            asm volatile("s_waitcnt lgkmcnt(0)" ::: "memory");
            __builtin_amdgcn_s_barrier();
            asm volatile("" ::: "memory");
        }
#undef STAGE_CC

        // sA is dead now -> carve reduction arrays out of it, zero, sync.
        if (t < 128) { red0[t] = 0.f; red1[t] = 0.f; }
        __syncthreads();

        int lab_n[2];
#pragma unroll
        for (int j = 0; j < 2; j++) lab_n[j] = label[bn * 64 + wn + j * 16 + fr];

#pragma unroll
        for (int i = 0; i < 4; i++) {
#pragma unroll
            for (int r3 = 0; r3 < 4; r3++) {
                const int ml = wm + i * 16 + quad * 4 + r3;
                const int mg = bm * 128 + ml;
                const int lm = label[mg];
                float ms = 0.f, mc = 0.f;
#pragma unroll
                for (int j = 0; j < 2; j++) {
                    const int ng = bn * 64 + wn + j * 16 + fr;
                    float s = aq[i][j][r3] * ak[i][j][r3];
                    sim[(size_t)mg * BATCH + ng] = (f16)s;
                    if (lab_n[j] == lm) { ms += s; mc += 1.f; }
                    if (mg == ng) ap[mg] = s;   // unique writer; read next dispatch
                }
#pragma unroll
                for (int off = 1; off < 16; off <<= 1) {
                    ms += __shfl_xor(ms, off, 64);
                    mc += __shfl_xor(mc, off, 64);
                }
                if (fr == 0) {
                    atomicAdd(&red0[ml], ms);
                    atomicAdd(&red1[ml], mc);
                }
            }
        }
        __syncthreads();
        if (t < 128) {
            atomicAdd(&msum[bm * 128 + t], red0[t]);
            atomicAdd(&mcnt[bm * 128 + t], red1[t]);
        }
    }
}

// ============ CC pass 2 + finalize — 256 BLOCKS x 8 ROWS, RELAXED TICKET (R4 winner) ============
// Relaxed ticket (no acq_rel L2 writeback+invalidate poison); per-thread cam/sam/label
// column table computed once in regs, reused across 8 rows; 8 sim-row loads up front.
__global__ __launch_bounds__(256) void cc_pass2_kernel(const f16* __restrict__ sim,
                                                       const int* __restrict__ label,
                                                       const float* __restrict__ msum,
                                                       const float* __restrict__ mcnt,
                                                       const float* __restrict__ ap,
                                                       const float* __restrict__ sumexp,
                                                       const float* __restrict__ sumlogit,
                                                       const float* __restrict__ philab,
                                                       float* __restrict__ znP,
                                                       float* __restrict__ znegP,
                                                       float* __restrict__ accAP,
                                                       unsigned* __restrict__ tick,
                                                       float* __restrict__ out) {
    __shared__ float sh[4];
    const int t = threadIdx.x, b = blockIdx.x;   // 256 blocks, rows b*8..b*8+7
    const int r0 = b * 8;

    // ---- per-thread COLUMN table (cols j = t*8..t*8+7), computed once, reused for 8 rows ----
    const int4 l0 = ((const int4*)label)[t * 2];
    const int4 l1 = ((const int4*)label)[t * 2 + 1];
    const f32x4 ms0 = ((const f32x4*)msum)[t * 2];
    const f32x4 ms1 = ((const f32x4*)msum)[t * 2 + 1];
    const f32x4 mc0 = ((const f32x4*)mcnt)[t * 2];
    const f32x4 mc1 = ((const f32x4*)mcnt)[t * 2 + 1];

    // ---- 8 sim row-chunks, loads issued up front (ILP) ----
    f16x8 v[8];
#pragma unroll
    for (int r = 0; r < 8; r++)
        v[r] = ((const f16x8*)(sim + (size_t)(r0 + r) * BATCH))[t];

    int lj[8];
    float caj[8], saj[8];
#pragma unroll
    for (int e = 0; e < 8; e++) {
        lj[e] = (e < 4) ? ((const int*)&l0)[e] : ((const int*)&l1)[e - 4];
        const float msj = (e < 4) ? ms0[e] : ms1[e - 4];
        const float mcj = (e < 4) ? mc0[e] : mc1[e - 4];
        caj[e] = clampf(msj / mcj, 0.f, 1.f);
        saj[e] = sqrtf(clampf(1.f - caj[e], 0.f, 1.f));
    }

    float acc = 0.f;
#pragma unroll
    for (int r = 0; r < 8; r++) {
        const int li = label[r0 + r];
#pragma unroll
        for (int e = 0; e < 8; e++) {
            if (lj[e] != li) {
                float can = clampf((float)v[r][e], 0.f, 1.f);
                float san = sqrtf(clampf(1.f - can, 0.f, 1.f));
                float pns = san * caj[e] + can * saj[e];          // column-j broadcast
                float pnc = sqrtf(clampf(1.f - pns, 0.f, 1.f));
                acc += __expf(pns * F_COS_M - pnc * F_SIN_M);
            }
        }
    }
    acc = blk_sum(acc, sh, t);

    // ---- per-row finalize: lanes 0..7 handle rows r0..r0+7; bucket atomics (8-deep) ----
    const int bk = b & 31;
    if (t < 8) {
        const int rr = r0 + t;
        float lse = logf(sumexp[rr]);
        float apart = 0.9f * (philab[rr] - lse) + 1e-5f * (sumlogit[rr] - (float)NCLS * lse);
        float cam = clampf(msum[rr] / mcnt[rr], 0.f, 1.f);
        float sam = sqrtf(clampf(1.f - cam, 0.f, 1.f));
        float cap = clampf(ap[rr], 0.f, 1.f);
        float sap = sqrtf(clampf(1.f - cap, 0.f, 1.f));
        float ppc = cap * cam - sap * sam;
        float pps = sqrtf(clampf(1.f - ppc, 0.f, 1.f));
        float epart = __expf(1.f - (ppc * F_COS_M - pps * F_SIN_M));

        if (t == 0) atomicAdd(&znP[bk], acc);
        atomicAdd(&accAP[bk], apart);
        atomicAdd(&znegP[bk], epart);
    }
    if (t == 0) {
        // bucket RMWs are device-scope atomics performed at the coherence point; waiting
        // their acks makes them globally visible WITHOUT any L2 writeback/invalidate.
        asm volatile("s_waitcnt vmcnt(0)" ::: "memory");
        unsigned old = __hip_atomic_fetch_add(tick, 1u, __ATOMIC_RELAXED, __HIP_MEMORY_SCOPE_AGENT);
        if (old == 255u) {   // last block
            float znv = 0.f, aav = 0.f, zgv = 0.f;
            for (int k = 0; k < 32; k++) {
                znv += __hip_atomic_load(znP + k,   __ATOMIC_RELAXED, __HIP_MEMORY_SCOPE_AGENT);
                aav += __hip_atomic_load(accAP + k, __ATOMIC_RELAXED, __HIP_MEMORY_SCOPE_AGENT);
                zgv += __hip_atomic_load(znegP + k, __ATOMIC_RELAXED, __HIP_MEMORY_SCOPE_AGENT);
            }
            float aam = -aav / (float)BATCH;
            float z = logf(znv) + logf(zgv);
            float cc = (z > 0.f) ? (z + log1pf(__expf(-z))) : log1pf(__expf(z));
            out[0] = aam + cc;
        }
    }
}

extern "C" void kernel_launch(void* const* d_in, const int* in_sizes, int n_in,
                              void* d_out, int out_size, void* d_ws, size_t ws_size,
                              hipStream_t stream) {
    const float* x        = (const float*)d_in[0];
    const int*   label    = (const int*)d_in[1];
    const float* weight   = (const float*)d_in[2];
    const float* weight_m = (const float*)d_in[3];
    const float* weight_n = (const float*)d_in[4];
    float* out = (float*)d_out;
    char* ws = (char*)d_ws;

    // compact ws (~17 MB): fp8 operands + fp16 sim + misc
    const size_t o_xnb  = 0;                                   // 1 MB
    const size_t o_wb   = o_xnb + (size_t)BATCH * DIM;         // 5.24 MB
    const size_t o_wqb  = o_wb  + (size_t)NPAD * DIM;          // 1 MB
    const size_t o_wkb  = o_wqb + (size_t)BATCH * DIM;         // 1 MB
    const size_t o_sim  = o_wkb + (size_t)BATCH * DIM;         // 8.39 MB (fp16)
    const size_t o_misc = o_sim + (size_t)BATCH * BATCH * 2;

    u8* xnb = (u8*)(ws + o_xnb);
    u8* wb  = (u8*)(ws + o_wb);
    u8* wqb = (u8*)(ws + o_wqb);
    u8* wkb = (u8*)(ws + o_wkb);
    f16* sim = (f16*)(ws + o_sim);
    float* mf  = (float*)(ws + o_misc);

    // zeroed by norm_all (33*256 = 8448 floats >= 8385 used)
    float* sumexp   = mf;               // 2048
    float* sumlogit = mf + 2048;        // 2048
    float* msum     = mf + 4096;        // 2048
    float* mcnt     = mf + 6144;        // 2048
    float* znP      = mf + 8192;        // 32 buckets
    float* znegP    = mf + 8224;        // 32 buckets
    float* accAP    = mf + 8256;        // 32 buckets
    unsigned* tick  = (unsigned*)(mf + 8288);
    // non-zeroed (fully overwritten every launch)
    float* philab  = mf + 8448;         // 2048
    float* ap      = mf + 10496;        // 2048

    norm_all_kernel<<<(BATCH + NPAD + 2 * BATCH) / 4, 256, 0, stream>>>(
        x, weight, weight_m, weight_n, label, xnb, wb, wqb, wkb, mf);

    gemm_fused_kernel<<<G_AAM + G_CC, 256, 0, stream>>>(
        xnb, wb, wqb, wkb, label,
        sumexp, sumlogit, philab, sim, msum, mcnt, ap);

    cc_pass2_kernel<<<256, 256, 0, stream>>>(
        sim, label, msum, mcnt, ap,
        sumexp, sumlogit, philab, znP, znegP, accAP, tick, out);
}

// Round 7
// 152.231 us; speedup vs baseline: 1.5198x; 1.5198x over previous
//
#include <hip/hip_runtime.h>
#include <hip/hip_bf16.h>

typedef unsigned short u16;
typedef unsigned char u8;
typedef unsigned int u32;
typedef _Float16 f16;
typedef _Float16 f16x8 __attribute__((ext_vector_type(8)));
typedef float f32x4 __attribute__((ext_vector_type(4)));
typedef unsigned int u32x4 __attribute__((ext_vector_type(4)));
typedef unsigned int u32x2 __attribute__((ext_vector_type(2)));
typedef long v2i64 __attribute__((ext_vector_type(2)));

constexpr int BATCH = 2048;
constexpr int DIM   = 512;
constexpr int NCLS  = 10000;
constexpr int NPAD  = 10240;   // 80 * 128 (zero-padded rows)

#define F_S     30.0f
#define F_COS_M 0.9800665778412416f
#define F_SIN_M 0.19866933079506122f
#define F_TH   (-0.9800665778412416f)
#define F_MM    0.03973386615901224f

#define G_AAM  1280   // 16 bm x 80 bn (128x128 tiles)
#define G_CC    512   // 16 bm x 32 bn (128x64 tiles)

static __device__ __forceinline__ float clampf(float v, float lo, float hi) {
    return fminf(fmaxf(v, lo), hi);
}
static __device__ __forceinline__ u32 pk4_fp8(float a, float b, float c, float d) {
    u32 w = __builtin_amdgcn_cvt_pk_fp8_f32(a, b, 0, false);
    w = __builtin_amdgcn_cvt_pk_fp8_f32(c, d, w, true);
    return w;
}
// async global->LDS, 16B/lane. DEST must be wave-uniform base + lane*16; SOURCE may scatter per-lane.
static __device__ __forceinline__ void glds16(const void* g, void* l) {
    __builtin_amdgcn_global_load_lds(
        (const __attribute__((address_space(1))) unsigned int*)g,
        (__attribute__((address_space(3))) unsigned int*)l, 16, 0, 0);
}
static __device__ __forceinline__ float blk_sum(float v, float* sh, int t) {
#pragma unroll
    for (int o = 32; o > 0; o >>= 1) v += __shfl_down(v, o, 64);
    __syncthreads();
    if ((t & 63) == 0) sh[t >> 6] = v;
    __syncthreads();
    return sh[0] + sh[1] + sh[2] + sh[3];
}

// ============ normalize: one WAVE per row -> fp8 e4m3, ks-interleaved rows, COALESCED stores ============
// Byte blk*64+q*16+ks*8 holds k=blk*64+ks*32+q*8 (same permutation for ALL matrices -> dot invariant),
// realized via lane-permute shfl so stores stay lane-contiguous.
__global__ __launch_bounds__(256) void norm_all_kernel(const float* __restrict__ x,
                                                       const float* __restrict__ w,
                                                       const float* __restrict__ wm,
                                                       const float* __restrict__ wn,
                                                       const int* __restrict__ label,
                                                       u8* __restrict__ xnb,
                                                       u8* __restrict__ wb,
                                                       u8* __restrict__ wqb,
                                                       u8* __restrict__ wkb,
                                                       float* __restrict__ zacc) {
    const int t = threadIdx.x, lane = t & 63, wv = t >> 6;
    const int b = blockIdx.x;
    if (b < 33) zacc[b * 256 + t] = 0.f;   // zero accumulators (8448 >= 8385 used)

    const int row = b * 4 + wv;
    const float* src;
    u8* dst;
    if (row < BATCH) {
        src = x + (size_t)row * DIM;
        dst = xnb + (size_t)row * DIM;
    } else if (row < BATCH + NPAD) {
        const int r = row - BATCH;
        dst = wb + (size_t)r * DIM;
        if (r >= NCLS) {   // zero pad rows (wave-uniform)
            u32x2 z = {0, 0};
            *(u32x2*)(dst + lane * 8) = z;
            return;
        }
        src = w + (size_t)r * DIM;
    } else if (row < BATCH + NPAD + BATCH) {
        const int i = row - (BATCH + NPAD);
        src = wm + (size_t)label[i] * DIM;
        dst = wqb + (size_t)i * DIM;
    } else {
        const int i = row - (BATCH + NPAD + BATCH);
        src = wn + (size_t)label[i] * DIM;
        dst = wkb + (size_t)i * DIM;
    }
    const float4 v0 = ((const float4*)src)[lane * 2];
    const float4 v1 = ((const float4*)src)[lane * 2 + 1];
    float s = v0.x * v0.x + v0.y * v0.y + v0.z * v0.z + v0.w * v0.w
            + v1.x * v1.x + v1.y * v1.y + v1.z * v1.z + v1.w * v1.w;
#pragma unroll
    for (int o = 32; o > 0; o >>= 1) s += __shfl_xor(s, o, 64);
    const float inv = 1.0f / fmaxf(sqrtf(s), 1e-12f);
    u32 lo = pk4_fp8(v0.x * inv, v0.y * inv, v0.z * inv, v0.w * inv);
    u32 hi = pk4_fp8(v1.x * inv, v1.y * inv, v1.z * inv, v1.w * inv);
    const int p = 8 * (lane >> 3) + 4 * (lane & 1) + ((lane >> 1) & 3);
    u32x2 o2;
    o2[0] = __shfl(lo, p, 64);
    o2[1] = __shfl(hi, p, 64);
    *(u32x2*)(dst + lane * 8) = o2;
}

// ============ FUSED fp8 GEMM, BK=64 DOUBLE-BUFFERED pipeline (T3+T4+T5) ============
// [0,1280)=AAM 128x128, [1280,1792)=CC 128x64.
// Per K-step: issue next tile's 4 global_load_lds -> s_waitcnt vmcnt(4) (counted: current
// tile landed, NEXT tile stays in flight across the barrier) -> raw s_barrier -> ds_read
// + setprio(1) MFMA setprio(0) -> lgkmcnt(0) + s_barrier.
// LDS = EXACTLY 32768 B (2x8K A + 2x8K B): red0/red1 ALIASED into dead sA[0] post-K-loop
// -> LDS allows 5 blocks/CU. launch_bounds stays (256,4): R6 showed (256,5) caps VGPR at 48
// and SPILLS the 64-VGPR accumulator (WRITE_SIZE 10->293 MB, 43->123 us). With VGPR=64 the
// HW scheduler still places 5 blocks/CU (LDS-limited), giving 20 waves/CU without spill.
__global__ __launch_bounds__(256, 4) void gemm_fused_kernel(const u8* __restrict__ A,
                                                            const u8* __restrict__ Bw,
                                                            const u8* __restrict__ Bq,
                                                            const u8* __restrict__ Bk,
                                                            const int* __restrict__ label,
                                                            float* __restrict__ sumexp,
                                                            float* __restrict__ sumlogit,
                                                            float* __restrict__ philab,
                                                            f16* __restrict__ sim,
                                                            float* __restrict__ msum,
                                                            float* __restrict__ mcnt,
                                                            float* __restrict__ ap) {
    __shared__ __align__(16) u8 sA[2][8192];   // 16 KB (dbuf A: 128 rows x 64B); epilogue: red0/red1
    __shared__ __align__(16) u8 sB[2][8192];   // 16 KB (AAM: B 128x64B; CC: Q=[0,4K), K=[4K,8K))
    float* red0 = (float*)&sA[0][0];           // 128 floats, valid ONLY after K-loop
    float* red1 = (float*)&sA[0][512];         // 128 floats

    const int t = threadIdx.x;
    const int lane = t & 63, wave = t >> 6;
    const int fr = lane & 15, quad = lane >> 4;
    const int gl = quad ^ ((fr >> 1) & 3);      // read-side swizzled 16B granule (of 4)

    const int srow = t >> 2;                    // 0..63 (+64 on second shot)
    const int sg   = (t & 3) ^ ((t >> 3) & 3);  // store-side swizzled source granule

    if (blockIdx.x < G_AAM) {
        // ---------------- AAM: 128x128 tile, BK=64 dbuf, 8 kb ----------------
        const int flat = blockIdx.x;
        const int xcd = flat & 7, r = flat >> 3;
        const int bm = r & 15;
        const int bn = (r >> 4) * 8 + xcd;       // 10 bn per xcd -> per-XCD L2-resident

        const int wm = (wave >> 1) * 64, wn = (wave & 1) * 64;
        const u8* ag = A  + (size_t)(bm * 128 + srow) * DIM + sg * 16;
        const u8* bg = Bw + (size_t)(bn * 128 + srow) * DIM + sg * 16;

        f32x4 acc[4][4] = {};

#define STAGE_AAM(buf, ko)                                              \
        do {                                                            \
            glds16(ag + (ko),            &sA[buf][t * 16]);             \
            glds16(ag + 64 * DIM + (ko), &sA[buf][4096 + t * 16]);      \
            glds16(bg + (ko),            &sB[buf][t * 16]);             \
            glds16(bg + 64 * DIM + (ko), &sB[buf][4096 + t * 16]);      \
        } while (0)

        STAGE_AAM(0, 0);
#pragma unroll
        for (int kb = 0; kb < 8; kb++) {
            const int cur = kb & 1;
            if (kb < 7) {
                STAGE_AAM(cur ^ 1, (kb + 1) * 64);
                asm volatile("s_waitcnt vmcnt(4)" ::: "memory");   // current tile landed; next stays in flight
            } else {
                asm volatile("s_waitcnt vmcnt(0)" ::: "memory");
            }
            __builtin_amdgcn_s_barrier();
            asm volatile("" ::: "memory");       // pin ds_reads below the barrier

            const u8* sAc = sA[cur];
            const u8* sBc = sB[cur];
            v2i64 a8[4], b8[4];
#pragma unroll
            for (int f = 0; f < 4; f++) {
                a8[f] = __builtin_bit_cast(v2i64, *(const u32x4*)&sAc[(wm + f * 16 + fr) * 64 + gl * 16]);
                b8[f] = __builtin_bit_cast(v2i64, *(const u32x4*)&sBc[(wn + f * 16 + fr) * 64 + gl * 16]);
            }
            __builtin_amdgcn_s_setprio(1);
#pragma unroll
            for (int i = 0; i < 4; i++)
#pragma unroll
                for (int j = 0; j < 4; j++) {
                    acc[i][j] = __builtin_amdgcn_mfma_f32_16x16x32_fp8_fp8(a8[i][0], b8[j][0], acc[i][j], 0, 0, 0);
                    acc[i][j] = __builtin_amdgcn_mfma_f32_16x16x32_fp8_fp8(a8[i][1], b8[j][1], acc[i][j], 0, 0, 0);
                }
            __builtin_amdgcn_s_setprio(0);
            asm volatile("s_waitcnt lgkmcnt(0)" ::: "memory");     // our reads consumed -> buffer reusable
            __builtin_amdgcn_s_barrier();
            asm volatile("" ::: "memory");       // pin next stage below the barrier
        }
#undef STAGE_AAM

        // sA is dead now -> carve reduction arrays out of it, zero, sync.
        if (t < 128) { red0[t] = 0.f; red1[t] = 0.f; }
        __syncthreads();

        // Epilogue: per-row partial Σexp(logit), Σlogit (logits<=30 -> fp32 safe, no max-sub)
#pragma unroll
        for (int i = 0; i < 4; i++) {
#pragma unroll
            for (int r3 = 0; r3 < 4; r3++) {
                const int ml = wm + i * 16 + quad * 4 + r3;
                const int mg = bm * 128 + ml;
                const int lab = label[mg];
                float esum = 0.f, lsum = 0.f;
#pragma unroll
                for (int j = 0; j < 4; j++) {
                    const int ng = bn * 128 + wn + j * 16 + fr;
                    if (ng < NCLS) {
                        float cv = acc[i][j][r3];
                        float logit;
                        if (ng == lab) {
                            float sine = sqrtf(clampf(1.f - cv * cv, 0.f, 1.f));
                            float phi = cv * F_COS_M - sine * F_SIN_M;
                            float val = ((cv - F_TH) > 0.f) ? phi : (cv - F_MM);
                            logit = F_S * val;
                            philab[mg] = logit;
                        } else {
                            logit = F_S * cv;
                        }
                        esum += __expf(logit);
                        lsum += logit;
                    }
                }
#pragma unroll
                for (int off = 1; off < 16; off <<= 1) {
                    esum += __shfl_xor(esum, off, 64);
                    lsum += __shfl_xor(lsum, off, 64);
                }
                if (fr == 0) {
                    atomicAdd(&red0[ml], esum);
                    atomicAdd(&red1[ml], lsum);
                }
            }
        }
        __syncthreads();
        if (t < 128) {
            atomicAdd(&sumexp[bm * 128 + t], red0[t]);
            atomicAdd(&sumlogit[bm * 128 + t], red1[t]);
        }
    } else {
        // ---------------- CC: dual GEMM, 128x64 tile, BK=64 dbuf, 8 kb ----------------
        const int c = blockIdx.x - G_AAM;
        const int xcd = c & 7, r = c >> 3;
        const int bm = r & 15;
        const int bn = (r >> 4) * 8 + xcd;       // 0..31

        const int wm = (wave >> 1) * 64, wn = (wave & 1) * 32;

        const u8* ag = A  + (size_t)(bm * 128 + srow) * DIM + sg * 16;
        const u8* qg = Bq + (size_t)(bn * 64 + srow) * DIM + sg * 16;
        const u8* kg = Bk + (size_t)(bn * 64 + srow) * DIM + sg * 16;

        f32x4 aq[4][2] = {};
        f32x4 ak[4][2] = {};

#define STAGE_CC(buf, ko)                                               \
        do {                                                            \
            glds16(ag + (ko),            &sA[buf][t * 16]);             \
            glds16(ag + 64 * DIM + (ko), &sA[buf][4096 + t * 16]);      \
            glds16(qg + (ko),            &sB[buf][t * 16]);             \
            glds16(kg + (ko),            &sB[buf][4096 + t * 16]);      \
        } while (0)

        STAGE_CC(0, 0);
#pragma unroll
        for (int kb = 0; kb < 8; kb++) {
            const int cur = kb & 1;
            if (kb < 7) {
                STAGE_CC(cur ^ 1, (kb + 1) * 64);
                asm volatile("s_waitcnt vmcnt(4)" ::: "memory");
            } else {
                asm volatile("s_waitcnt vmcnt(0)" ::: "memory");
            }
            __builtin_amdgcn_s_barrier();
            asm volatile("" ::: "memory");

            const u8* sAc = sA[cur];
            const u8* sBc = sB[cur];
            v2i64 a8[4], q8[2], k8[2];
#pragma unroll
            for (int f = 0; f < 4; f++)
                a8[f] = __builtin_bit_cast(v2i64, *(const u32x4*)&sAc[(wm + f * 16 + fr) * 64 + gl * 16]);
#pragma unroll
            for (int f = 0; f < 2; f++) {
                q8[f] = __builtin_bit_cast(v2i64, *(const u32x4*)&sBc[(wn + f * 16 + fr) * 64 + gl * 16]);
                k8[f] = __builtin_bit_cast(v2i64, *(const u32x4*)&sBc[4096 + (wn + f * 16 + fr) * 64 + gl * 16]);
            }
            __builtin_amdgcn_s_setprio(1);
#pragma unroll
            for (int i = 0; i < 4; i++)
#pragma unroll
                for (int j = 0; j < 2; j++) {
                    aq[i][j] = __builtin_amdgcn_mfma_f32_16x16x32_fp8_fp8(a8[i][0], q8[j][0], aq[i][j], 0, 0, 0);
                    aq[i][j] = __builtin_amdgcn_mfma_f32_16x16x32_fp8_fp8(a8[i][1], q8[j][1], aq[i][j], 0, 0, 0);
                    ak[i][j] = __builtin_amdgcn_mfma_f32_16x16x32_fp8_fp8(a8[i][0], k8[j][0], ak[i][j], 0, 0, 0);
                    ak[i][j] = __builtin_amdgcn_mfma_f32_16x16x32_fp8_fp8(a8[i][1], k8[j][1], ak[i][j], 0, 0, 0);
                }
            __builtin_amdgcn_s_setprio(0);
            asm volatile("s_waitcnt lgkmcnt(0)" ::: "memory");
            __builtin_amdgcn_s_barrier();
            asm volatile("" ::: "memory");
        }
#undef STAGE_CC

        // sA is dead now -> carve reduction arrays out of it, zero, sync.
        if (t < 128) { red0[t] = 0.f; red1[t] = 0.f; }
        __syncthreads();

        int lab_n[2];
#pragma unroll
        for (int j = 0; j < 2; j++) lab_n[j] = label[bn * 64 + wn + j * 16 + fr];

#pragma unroll
        for (int i = 0; i < 4; i++) {
#pragma unroll
            for (int r3 = 0; r3 < 4; r3++) {
                const int ml = wm + i * 16 + quad * 4 + r3;
                const int mg = bm * 128 + ml;
                const int lm = label[mg];
                float ms = 0.f, mc = 0.f;
#pragma unroll
                for (int j = 0; j < 2; j++) {
                    const int ng = bn * 64 + wn + j * 16 + fr;
                    float s = aq[i][j][r3] * ak[i][j][r3];
                    sim[(size_t)mg * BATCH + ng] = (f16)s;
                    if (lab_n[j] == lm) { ms += s; mc += 1.f; }
                    if (mg == ng) ap[mg] = s;   // unique writer; read next dispatch
                }
#pragma unroll
                for (int off = 1; off < 16; off <<= 1) {
                    ms += __shfl_xor(ms, off, 64);
                    mc += __shfl_xor(mc, off, 64);
                }
                if (fr == 0) {
                    atomicAdd(&red0[ml], ms);
                    atomicAdd(&red1[ml], mc);
                }
            }
        }
        __syncthreads();
        if (t < 128) {
            atomicAdd(&msum[bm * 128 + t], red0[t]);
            atomicAdd(&mcnt[bm * 128 + t], red1[t]);
        }
    }
}

// ============ CC pass 2 + finalize — 256 BLOCKS x 8 ROWS, RELAXED TICKET (R4 winner) ============
// Relaxed ticket (no acq_rel L2 writeback+invalidate poison); per-thread cam/sam/label
// column table computed once in regs, reused across 8 rows; 8 sim-row loads up front.
__global__ __launch_bounds__(256) void cc_pass2_kernel(const f16* __restrict__ sim,
                                                       const int* __restrict__ label,
                                                       const float* __restrict__ msum,
                                                       const float* __restrict__ mcnt,
                                                       const float* __restrict__ ap,
                                                       const float* __restrict__ sumexp,
                                                       const float* __restrict__ sumlogit,
                                                       const float* __restrict__ philab,
                                                       float* __restrict__ znP,
                                                       float* __restrict__ znegP,
                                                       float* __restrict__ accAP,
                                                       unsigned* __restrict__ tick,
                                                       float* __restrict__ out) {
    __shared__ float sh[4];
    const int t = threadIdx.x, b = blockIdx.x;   // 256 blocks, rows b*8..b*8+7
    const int r0 = b * 8;

    // ---- per-thread COLUMN table (cols j = t*8..t*8+7), computed once, reused for 8 rows ----
    const int4 l0 = ((const int4*)label)[t * 2];
    const int4 l1 = ((const int4*)label)[t * 2 + 1];
    const f32x4 ms0 = ((const f32x4*)msum)[t * 2];
    const f32x4 ms1 = ((const f32x4*)msum)[t * 2 + 1];
    const f32x4 mc0 = ((const f32x4*)mcnt)[t * 2];
    const f32x4 mc1 = ((const f32x4*)mcnt)[t * 2 + 1];

    // ---- 8 sim row-chunks, loads issued up front (ILP) ----
    f16x8 v[8];
#pragma unroll
    for (int r = 0; r < 8; r++)
        v[r] = ((const f16x8*)(sim + (size_t)(r0 + r) * BATCH))[t];

    int lj[8];
    float caj[8], saj[8];
#pragma unroll
    for (int e = 0; e < 8; e++) {
        lj[e] = (e < 4) ? ((const int*)&l0)[e] : ((const int*)&l1)[e - 4];
        const float msj = (e < 4) ? ms0[e] : ms1[e - 4];
        const float mcj = (e < 4) ? mc0[e] : mc1[e - 4];
        caj[e] = clampf(msj / mcj, 0.f, 1.f);
        saj[e] = sqrtf(clampf(1.f - caj[e], 0.f, 1.f));
    }

    float acc = 0.f;
#pragma unroll
    for (int r = 0; r < 8; r++) {
        const int li = label[r0 + r];
#pragma unroll
        for (int e = 0; e < 8; e++) {
            if (lj[e] != li) {
                float can = clampf((float)v[r][e], 0.f, 1.f);
                float san = sqrtf(clampf(1.f - can, 0.f, 1.f));
                float pns = san * caj[e] + can * saj[e];          // column-j broadcast
                float pnc = sqrtf(clampf(1.f - pns, 0.f, 1.f));
                acc += __expf(pns * F_COS_M - pnc * F_SIN_M);
            }
        }
    }
    acc = blk_sum(acc, sh, t);

    // ---- per-row finalize: lanes 0..7 handle rows r0..r0+7; bucket atomics (8-deep) ----
    const int bk = b & 31;
    if (t < 8) {
        const int rr = r0 + t;
        float lse = logf(sumexp[rr]);
        float apart = 0.9f * (philab[rr] - lse) + 1e-5f * (sumlogit[rr] - (float)NCLS * lse);
        float cam = clampf(msum[rr] / mcnt[rr], 0.f, 1.f);
        float sam = sqrtf(clampf(1.f - cam, 0.f, 1.f));
        float cap = clampf(ap[rr], 0.f, 1.f);
        float sap = sqrtf(clampf(1.f - cap, 0.f, 1.f));
        float ppc = cap * cam - sap * sam;
        float pps = sqrtf(clampf(1.f - ppc, 0.f, 1.f));
        float epart = __expf(1.f - (ppc * F_COS_M - pps * F_SIN_M));

        if (t == 0) atomicAdd(&znP[bk], acc);
        atomicAdd(&accAP[bk], apart);
        atomicAdd(&znegP[bk], epart);
    }
    if (t == 0) {
        // bucket RMWs are device-scope atomics performed at the coherence point; waiting
        // their acks makes them globally visible WITHOUT any L2 writeback/invalidate.
        asm volatile("s_waitcnt vmcnt(0)" ::: "memory");
        unsigned old = __hip_atomic_fetch_add(tick, 1u, __ATOMIC_RELAXED, __HIP_MEMORY_SCOPE_AGENT);
        if (old == 255u) {   // last block
            float znv = 0.f, aav = 0.f, zgv = 0.f;
            for (int k = 0; k < 32; k++) {
                znv += __hip_atomic_load(znP + k,   __ATOMIC_RELAXED, __HIP_MEMORY_SCOPE_AGENT);
                aav += __hip_atomic_load(accAP + k, __ATOMIC_RELAXED, __HIP_MEMORY_SCOPE_AGENT);
                zgv += __hip_atomic_load(znegP + k, __ATOMIC_RELAXED, __HIP_MEMORY_SCOPE_AGENT);
            }
            float aam = -aav / (float)BATCH;
            float z = logf(znv) + logf(zgv);
            float cc = (z > 0.f) ? (z + log1pf(__expf(-z))) : log1pf(__expf(z));
            out[0] = aam + cc;
        }
    }
}

extern "C" void kernel_launch(void* const* d_in, const int* in_sizes, int n_in,
                              void* d_out, int out_size, void* d_ws, size_t ws_size,
                              hipStream_t stream) {
    const float* x        = (const float*)d_in[0];
    const int*   label    = (const int*)d_in[1];
    const float* weight   = (const float*)d_in[2];
    const float* weight_m = (const float*)d_in[3];
    const float* weight_n = (const float*)d_in[4];
    float* out = (float*)d_out;
    char* ws = (char*)d_ws;

    // compact ws (~17 MB): fp8 operands + fp16 sim + misc
    const size_t o_xnb  = 0;                                   // 1 MB
    const size_t o_wb   = o_xnb + (size_t)BATCH * DIM;         // 5.24 MB
    const size_t o_wqb  = o_wb  + (size_t)NPAD * DIM;          // 1 MB
    const size_t o_wkb  = o_wqb + (size_t)BATCH * DIM;         // 1 MB
    const size_t o_sim  = o_wkb + (size_t)BATCH * DIM;         // 8.39 MB (fp16)
    const size_t o_misc = o_sim + (size_t)BATCH * BATCH * 2;

    u8* xnb = (u8*)(ws + o_xnb);
    u8* wb  = (u8*)(ws + o_wb);
    u8* wqb = (u8*)(ws + o_wqb);
    u8* wkb = (u8*)(ws + o_wkb);
    f16* sim = (f16*)(ws + o_sim);
    float* mf  = (float*)(ws + o_misc);

    // zeroed by norm_all (33*256 = 8448 floats >= 8385 used)
    float* sumexp   = mf;               // 2048
    float* sumlogit = mf + 2048;        // 2048
    float* msum     = mf + 4096;        // 2048
    float* mcnt     = mf + 6144;        // 2048
    float* znP      = mf + 8192;        // 32 buckets
    float* znegP    = mf + 8224;        // 32 buckets
    float* accAP    = mf + 8256;        // 32 buckets
    unsigned* tick  = (unsigned*)(mf + 8288);
    // non-zeroed (fully overwritten every launch)
    float* philab  = mf + 8448;         // 2048
    float* ap      = mf + 10496;        // 2048

    norm_all_kernel<<<(BATCH + NPAD + 2 * BATCH) / 4, 256, 0, stream>>>(
        x, weight, weight_m, weight_n, label, xnb, wb, wqb, wkb, mf);

    gemm_fused_kernel<<<G_AAM + G_CC, 256, 0, stream>>>(
        xnb, wb, wqb, wkb, label,
        sumexp, sumlogit, philab, sim, msum, mcnt, ap);

    cc_pass2_kernel<<<256, 256, 0, stream>>>(
        sim, label, msum, mcnt, ap,
        sumexp, sumlogit, philab, znP, znegP, accAP, tick, out);
}